// Round 2
// baseline (292.824 us; speedup 1.0000x reference)
//
#include <hip/hip_runtime.h>

#define NN 100000
#define NE 800000
#define NPAD 100096  // 782*128 = 6256*16, so GEMM row tiles / panels never read OOB
#define OCT 12544    // 8*12544 = 100352 >= NN ; dst/OCT = XCD octant

typedef __attribute__((ext_vector_type(8))) __bf16 bf16x8;
typedef __attribute__((ext_vector_type(4))) float f32x4;

__device__ __forceinline__ uint f2bf(float f) {  // f32 -> bf16 bits (RNE), low 16
  uint u = __float_as_uint(f);
  return (u + 0x7fffu + ((u >> 16) & 1u)) >> 16;
}
__device__ __forceinline__ float bflo(uint u) { return __uint_as_float(u << 16); }
__device__ __forceinline__ float bfhi(uint u) { return __uint_as_float(u & 0xffff0000u); }

// ---------------- CSR build (XCD-partitioned hist/scatter) ----------------
__global__ __launch_bounds__(256) void k_hist(const int* __restrict__ dst,
                                              int* __restrict__ deg) {
  int xcd = blockIdx.x & 7, chunk = blockIdx.x >> 3;
  int e0 = chunk * 2048 + threadIdx.x;
#pragma unroll
  for (int i = 0; i < 8; ++i) {
    int e = e0 + i * 256;
    if (e < NE) {
      int d = dst[e];
      if (d / OCT == xcd) atomicAdd(&deg[d], 1);
    }
  }
}

__global__ void k_scan_partial(const int* __restrict__ deg, int* __restrict__ bsum, int N) {
  __shared__ int s[256];
  int b = blockIdx.x, t = threadIdx.x;
  int base = b * 1024 + t * 4;
  int v = 0;
#pragma unroll
  for (int i = 0; i < 4; ++i) { int idx = base + i; if (idx < N) v += deg[idx]; }
  s[t] = v; __syncthreads();
  for (int o = 128; o > 0; o >>= 1) { if (t < o) s[t] += s[t + o]; __syncthreads(); }
  if (t == 0) bsum[b] = s[0];
}

__global__ void k_scan_bsums(const int* __restrict__ bsum, int* __restrict__ bpre,
                             int* __restrict__ offsets, int NB, int N) {
  __shared__ int s[128];
  int t = threadIdx.x;
  int v = (t < NB) ? bsum[t] : 0;
  s[t] = v; __syncthreads();
  for (int o = 1; o < 128; o <<= 1) {
    int add = (t >= o) ? s[t - o] : 0;
    __syncthreads();
    s[t] += add;
    __syncthreads();
  }
  if (t < NB) bpre[t] = s[t] - v;
  if (t == NB - 1) offsets[N] = s[t];
}

__global__ void k_scan_final(const int* __restrict__ deg, const int* __restrict__ bpre,
                             int* __restrict__ offsets, int* __restrict__ cursor, int N) {
  __shared__ int s[256];
  int b = blockIdx.x, t = threadIdx.x;
  int base = b * 1024 + t * 4;
  int v[4];
#pragma unroll
  for (int i = 0; i < 4; ++i) { int idx = base + i; v[i] = (idx < N) ? deg[idx] : 0; }
  int tsum = v[0] + v[1] + v[2] + v[3];
  s[t] = tsum; __syncthreads();
  for (int o = 1; o < 256; o <<= 1) {
    int add = (t >= o) ? s[t - o] : 0;
    __syncthreads();
    s[t] += add;
    __syncthreads();
  }
  int run = s[t] - tsum + bpre[b];
#pragma unroll
  for (int i = 0; i < 4; ++i) {
    int idx = base + i;
    if (idx < N) { offsets[idx] = run; cursor[idx] = run; }
    run += v[i];
  }
}

__global__ __launch_bounds__(256) void k_scatter(const int* __restrict__ src,
                                                 const int* __restrict__ dst,
                                                 int* __restrict__ cursor,
                                                 int* __restrict__ csr_src) {
  int xcd = blockIdx.x & 7, chunk = blockIdx.x >> 3;
  int e0 = chunk * 2048 + threadIdx.x;
#pragma unroll
  for (int i = 0; i < 8; ++i) {
    int e = e0 + i * 256;
    if (e < NE) {
      int d = dst[e];
      if (d / OCT == xcd) {
        int pos = atomicAdd(&cursor[d], 1);
        csr_src[pos] = src[e];
      }
    }
  }
}

// ---------------- converts ----------------
__global__ void k_cvt_x(const float* __restrict__ x, ushort* __restrict__ xb) {
  int i = blockIdx.x * 256 + threadIdx.x;  // group of 4 floats
  if (i >= NPAD * 32) return;
  int row = i >> 5;
  float4 v = (row < NN) ? ((const float4*)x)[i] : make_float4(0.f, 0.f, 0.f, 0.f);
  uint2 o;
  o.x = f2bf(v.x) | (f2bf(v.y) << 16);
  o.y = f2bf(v.z) | (f2bf(v.w) << 16);
  ((uint2*)xb)[i] = o;
}

// weights as STACKED [out][k] bf16, K=256 = [Wrel(128) ; Wroot(128)]:
// layout: [Wst1 128x256 = 32768][Wst2 256x256 = 65536][Wt3 32x256 = 8192]
__global__ void k_cvt_w(const float* __restrict__ Wr1, const float* __restrict__ Wo1,
                        const float* __restrict__ Wr2, const float* __restrict__ Wo2,
                        const float* __restrict__ Wr3, const float* __restrict__ Wo3,
                        ushort* __restrict__ t) {
  int idx = blockIdx.x * 256 + threadIdx.x;
  if (idx >= 106496) return;
  float v;
  if (idx < 32768) {        // Wst1 [o<128][k<256]
    int o = idx >> 8, k = idx & 255;
    v = (k < 128) ? Wr1[(size_t)k * 128 + o] : Wo1[(size_t)(k - 128) * 128 + o];
  } else if (idx < 98304) {  // Wst2 [o<256][k<256]
    int li = idx - 32768;
    int o = li >> 8, k = li & 255;
    v = (k < 128) ? Wr2[(size_t)k * 256 + o] : Wo2[(size_t)(k - 128) * 256 + o];
  } else {                   // Wt3 [32][256]: o<16 -> Wrel3 col o ; o>=16 -> Wroot3 col o-16
    int li = idx - 98304;
    int o = li >> 8, k = li & 255;
    v = (o < 16) ? Wr3[(size_t)k * 16 + o] : Wo3[(size_t)k * 16 + (o - 16)];
  }
  t[idx] = (ushort)f2bf(v);
}

// ------- aggregation + root concat: ag[n] = [sum_{j in N(n)} X_j (K 0..127) | X_n (K 128..255)]
// written in GEMM panel layout: element (row,k) at byte
//   (row>>4)*8192 + (k>>3)*256 + (row&15)*16 + (k&7)*2
// 16-node block == exactly one panel; per-wave stores are complete 64B segments.
#define ACC8(q)                      \
  do {                               \
    acc[0] += bflo(q.x); acc[1] += bfhi(q.x); \
    acc[2] += bflo(q.y); acc[3] += bfhi(q.y); \
    acc[4] += bflo(q.z); acc[5] += bfhi(q.z); \
    acc[6] += bflo(q.w); acc[7] += bfhi(q.w); \
  } while (0)

__global__ __launch_bounds__(256) void k_aggcat(const ushort* __restrict__ X,
                                                const int* __restrict__ offsets,
                                                const int* __restrict__ csr,
                                                ushort* __restrict__ ag) {
  int tid = threadIdx.x;
  int sg = tid >> 4, fl = tid & 15;
  int n = blockIdx.x * 16 + sg;
  uint4* AG = (uint4*)ag;
  // uint4 index: panel*512 + chunk*16 + (n&15)
  size_t ob = (size_t)(n >> 4) * 512 + (size_t)fl * 16 + (n & 15);
  if (n >= NN) {
    uint4 z = make_uint4(0u, 0u, 0u, 0u);
    AG[ob] = z;        // agg half, chunk fl
    AG[ob + 256] = z;  // root half, chunk 16+fl
    return;
  }
  int o0 = offsets[n], o1 = offsets[n + 1];
  const uint4* X4 = (const uint4*)X;
  float acc[8];
#pragma unroll
  for (int k = 0; k < 8; ++k) acc[k] = 0.f;
  int j = o0;
  if (j + 3 < o1) {
    uint4 q0 = X4[(size_t)csr[j] * 16 + fl];
    uint4 q1 = X4[(size_t)csr[j + 1] * 16 + fl];
    uint4 q2 = X4[(size_t)csr[j + 2] * 16 + fl];
    uint4 q3 = X4[(size_t)csr[j + 3] * 16 + fl];
    j += 4;
    while (j + 3 < o1) {
      uint4 p0 = X4[(size_t)csr[j] * 16 + fl];
      uint4 p1 = X4[(size_t)csr[j + 1] * 16 + fl];
      uint4 p2 = X4[(size_t)csr[j + 2] * 16 + fl];
      uint4 p3 = X4[(size_t)csr[j + 3] * 16 + fl];
      j += 4;
      ACC8(q0); ACC8(q1); ACC8(q2); ACC8(q3);
      q0 = p0; q1 = p1; q2 = p2; q3 = p3;
    }
    ACC8(q0); ACC8(q1); ACC8(q2); ACC8(q3);
  }
  for (; j < o1; ++j) {
    uint4 q = X4[(size_t)csr[j] * 16 + fl];
    ACC8(q);
  }
  uint4 own = X4[(size_t)n * 16 + fl];  // bf16 passthrough of own row
  uint4 o;
  o.x = f2bf(acc[0]) | (f2bf(acc[1]) << 16);
  o.y = f2bf(acc[2]) | (f2bf(acc[3]) << 16);
  o.z = f2bf(acc[4]) | (f2bf(acc[5]) << 16);
  o.w = f2bf(acc[6]) | (f2bf(acc[7]) << 16);
  AG[ob] = o;
  AG[ob + 256] = own;
}

// ---------------- MFMA GEMM: out = act(ag @ Wst + b), K=256, A in panel layout ----------------
// Every A-load is a wave-contiguous 1KB (8 full 128B lines): addr = panelbase + ks*1024 + lane*16
// lands directly in the mfma_16x16x32 A-fragment (row=lane&15, chunk=ks*4+lane>>4).
// W staged to LDS via global_load_lds (1KB contiguous) with both-sides XOR swizzle on 512B rows.
template <int RELU>
__global__ __launch_bounds__(512, 4) void k_gemm_mfma(
    const ushort* __restrict__ ag, const ushort* __restrict__ Wst,
    const float* __restrict__ bias, ushort* __restrict__ out, int OUT) {
  __shared__ ushort sW[128 * 256];  // 64KB: 128 outs x 256 k
  int tid = threadIdx.x;
  int r0 = blockIdx.x * 128;
  int c0 = blockIdx.y * 128;

  int lane = tid & 63, wid = tid >> 6;
  int cl = lane & 15, hi = lane >> 4;

  // full-K A prefetch: 8 x 16B per lane, each instruction = contiguous 1KB per wave
  const char* agB = (const char*)ag + ((size_t)(r0 >> 4) + wid) * 8192 + (size_t)lane * 16;
  bf16x8 A[8];
#pragma unroll
  for (int ks = 0; ks < 8; ++ks) A[ks] = *(const bf16x8*)(agB + ks * 1024);

  const char* gw = (const char*)(Wst + (size_t)c0 * 256);
#pragma unroll
  for (int i = 0; i < 8; ++i) {
    int L = (tid + i * 512) << 4;   // linear LDS byte in 64KB
    int o = L >> 9;                 // 512B out-row
    int gb = L ^ ((o & 15) << 4);   // pre-swizzled global source (involution)
    __builtin_amdgcn_global_load_lds((const __attribute__((address_space(1))) void*)(gw + gb),
                                     (__attribute__((address_space(3))) void*)((char*)sW + L), 16, 0, 0);
  }
  __syncthreads();  // the ONE wait point: drains A-regs + W-LDS together

  f32x4 zero = {0.f, 0.f, 0.f, 0.f};
  f32x4 acc[8];
#pragma unroll
  for (int j = 0; j < 8; ++j) acc[j] = zero;

#pragma unroll
  for (int ks = 0; ks < 8; ++ks) {
    int c = ks * 4 + hi;  // 16B k-chunk index
#pragma unroll
    for (int j = 0; j < 8; ++j) {
      int o = j * 16 + cl;
      bf16x8 wf = *(const bf16x8*)((const char*)sW + (o << 9) + ((c ^ (o & 15)) << 4));
      acc[j] = __builtin_amdgcn_mfma_f32_16x16x32_bf16(A[ks], wf, acc[j], 0, 0, 0);
    }
  }

  // epilogue: C/D layout col=lane&15, row=(lane>>4)*4+reg (m89); row-major out
#pragma unroll
  for (int j = 0; j < 8; ++j) {
    int col = c0 + j * 16 + cl;
    float bv = bias[col];
#pragma unroll
    for (int reg = 0; reg < 4; ++reg) {
      int row = r0 + wid * 16 + hi * 4 + reg;
      if (row < NN) {
        float v = acc[j][reg] + bv;
        if (RELU) v = fmaxf(v, 0.f);
        out[(size_t)row * OUT + col] = (ushort)f2bf(v);
      }
    }
  }
}

// ---------------- layer 3 MFMA: y3b = h2@Wrel3 (bf16); z(d_out) = h2@Wroot3 + b3 ----------------
__global__ __launch_bounds__(512) void k_l3m(const ushort* __restrict__ h2,
                                             const ushort* __restrict__ Wt3,
                                             const float* __restrict__ bias,
                                             ushort* __restrict__ y3b, float* __restrict__ z) {
  int tid = threadIdx.x;
  int lane = tid & 63, wid = tid >> 6;
  int cl = lane & 15, hi = lane >> 4;
  size_t row0 = ((size_t)blockIdx.x * 8 + wid) * 16;
  bf16x8 b0[8], b1[8];
#pragma unroll
  for (int ks = 0; ks < 8; ++ks) {
    b0[ks] = *(const bf16x8*)(Wt3 + cl * 256 + ks * 32 + hi * 8);
    b1[ks] = *(const bf16x8*)(Wt3 + (16 + cl) * 256 + ks * 32 + hi * 8);
  }
  const ushort* arow = h2 + (row0 + cl) * 256 + hi * 8;
  f32x4 acc0 = {0.f, 0.f, 0.f, 0.f}, acc1 = {0.f, 0.f, 0.f, 0.f};
#pragma unroll
  for (int ks = 0; ks < 8; ++ks) {
    bf16x8 a = *(const bf16x8*)(arow + ks * 32);
    acc0 = __builtin_amdgcn_mfma_f32_16x16x32_bf16(a, b0[ks], acc0, 0, 0, 0);
    acc1 = __builtin_amdgcn_mfma_f32_16x16x32_bf16(a, b1[ks], acc1, 0, 0, 0);
  }
  float bv = bias[cl];
#pragma unroll
  for (int reg = 0; reg < 4; ++reg) {
    size_t row = row0 + hi * 4 + reg;
    if (row < NN) {
      y3b[row * 16 + cl] = (ushort)f2bf(acc0[reg]);
      z[row * 16 + cl] = acc1[reg] + bv;
    }
  }
}

// ---------------- fused: out = log_softmax(z + segsum(y3b[src])) ----------------
__global__ void k_agg16lsm(const int* __restrict__ offsets, const int* __restrict__ csr,
                           const ushort* __restrict__ y3b, float* __restrict__ out) {
  int t = blockIdx.x * 256 + threadIdx.x;  // (node, uint-pair) : 8 lanes per node
  if (t >= NN * 8) return;
  int n = t >> 3, g = t & 7;
  int o0 = offsets[n], o1 = offsets[n + 1];
  float a0 = 0.f, a1 = 0.f;
  const uint* Y = (const uint*)y3b;
  for (int j = o0; j < o1; ++j) {
    uint u = Y[(size_t)csr[j] * 8 + g];
    a0 += bflo(u); a1 += bfhi(u);
  }
  float v0 = out[n * 16 + g * 2] + a0;
  float v1 = out[n * 16 + g * 2 + 1] + a1;
  float m = fmaxf(v0, v1);
#pragma unroll
  for (int mask = 1; mask < 8; mask <<= 1) m = fmaxf(m, __shfl_xor(m, mask));
  float s = __expf(v0 - m) + __expf(v1 - m);
#pragma unroll
  for (int mask = 1; mask < 8; mask <<= 1) s += __shfl_xor(s, mask);
  float ls = __logf(s);
  out[n * 16 + g * 2] = v0 - m - ls;
  out[n * 16 + g * 2 + 1] = v1 - m - ls;
}

extern "C" void kernel_launch(void* const* d_in, const int* in_sizes, int n_in,
                              void* d_out, int out_size, void* d_ws, size_t ws_size,
                              hipStream_t stream) {
  const float* x = (const float*)d_in[0];
  const int* ei = (const int*)d_in[1];  // [2][NE]: row0=src, row1=dst
  const float* Wrel1 = (const float*)d_in[2];
  const float* Wroot1 = (const float*)d_in[3];
  const float* b1 = (const float*)d_in[4];
  const float* Wrel2 = (const float*)d_in[5];
  const float* Wroot2 = (const float*)d_in[6];
  const float* b2 = (const float*)d_in[7];
  const float* Wrel3 = (const float*)d_in[8];
  const float* Wroot3 = (const float*)d_in[9];
  const float* b3 = (const float*)d_in[10];
  float* out = (float*)d_out;

  char* ws = (char*)d_ws;
  size_t off = 0;
  auto alloc = [&](size_t bytes) {
    void* p = ws + off;
    off += (bytes + 255) / 256 * 256;
    return p;
  };
  int* deg = (int*)alloc((size_t)NN * 4);
  int* offsets = (int*)alloc((size_t)(NN + 1) * 4);
  int* cursor = (int*)alloc((size_t)NN * 4);
  int* bsum = (int*)alloc(128 * 4);
  int* bpre = (int*)alloc(128 * 4);
  int* csr = (int*)alloc((size_t)NE * 4);
  ushort* xb = (ushort*)alloc((size_t)NPAD * 128 * 2);
  ushort* ag = (ushort*)alloc((size_t)NPAD * 256 * 2);   // panel-layout [agg|root], K=256
  ushort* h1b = (ushort*)alloc((size_t)NPAD * 128 * 2);
  ushort* h2b = (ushort*)alloc((size_t)NPAD * 256 * 2);
  ushort* y3b = (ushort*)alloc((size_t)NN * 16 * 2);
  ushort* wt = (ushort*)alloc((size_t)106496 * 2);
  ushort *Wst1 = wt, *Wst2 = wt + 32768;
  ushort* Wt3 = wt + 98304;

  const int* src = ei;
  const int* dst = ei + NE;

  // converts (independent of CSR)
  k_cvt_x<<<(NPAD * 32 + 255) / 256, 256, 0, stream>>>(x, xb);
  k_cvt_w<<<(106496 + 255) / 256, 256, 0, stream>>>(Wrel1, Wroot1, Wrel2, Wroot2, Wrel3,
                                                    Wroot3, wt);

  // CSR build (XCD-partitioned hist + scatter)
  hipMemsetAsync(deg, 0, (size_t)NN * 4, stream);
  int nchunk = (NE + 2047) / 2048;  // 391
  k_hist<<<8 * nchunk, 256, 0, stream>>>(dst, deg);
  int NB = (NN + 1023) / 1024;  // 98
  k_scan_partial<<<NB, 256, 0, stream>>>(deg, bsum, NN);
  k_scan_bsums<<<1, 128, 0, stream>>>(bsum, bpre, offsets, NB, NN);
  k_scan_final<<<NB, 256, 0, stream>>>(deg, bpre, offsets, cursor, NN);
  k_scatter<<<8 * nchunk, 256, 0, stream>>>(src, dst, cursor, csr);

  // layer 1: h1 = relu([agg(x)|x] @ [Wr1;Wo1] + b1)
  k_aggcat<<<NPAD / 16, 256, 0, stream>>>(xb, offsets, csr, ag);
  k_gemm_mfma<1><<<dim3(NPAD / 128, 1), 512, 0, stream>>>(ag, Wst1, b1, h1b, 128);
  // layer 2: h2 = relu([agg(h1)|h1] @ [Wr2;Wo2] + b2)
  k_aggcat<<<NPAD / 16, 256, 0, stream>>>(h1b, offsets, csr, ag);
  k_gemm_mfma<1><<<dim3(NPAD / 128, 2), 512, 0, stream>>>(ag, Wst2, b2, h2b, 256);
  // layer 3
  k_l3m<<<NPAD / 128, 512, 0, stream>>>(h2b, Wt3, b3, y3b, out);
  k_agg16lsm<<<(NN * 8 + 255) / 256, 256, 0, stream>>>(offsets, csr, y3b, out);
}